// Round 12
// baseline (205.120 us; speedup 1.0000x reference)
//
#include <hip/hip_runtime.h>
#include <hip/hip_bf16.h>
#include <stdint.h>

#define TB 2
#define TS 2048
#define TD 1024
#define TH 16
#define THS 64
#define TK 1024  // inner dim of both GEMMs

typedef __attribute__((ext_vector_type(8))) short short8;
typedef __attribute__((ext_vector_type(4))) short short4v;
typedef __attribute__((ext_vector_type(4))) float f32x4;
typedef __attribute__((ext_vector_type(16))) float f32x16;
typedef __attribute__((ext_vector_type(4))) unsigned int uint4v;

static __device__ __forceinline__ unsigned short f2bf(float f) {
  union { float f; unsigned u; } v; v.f = f;
  unsigned r = v.u + 0x7FFFu + ((v.u >> 16) & 1u);  // RTNE
  return (unsigned short)(r >> 16);
}

// pack two f32 -> (hi:bf16(b), lo:bf16(a))
static __device__ __forceinline__ unsigned cvtpk(float a, float b) {
  unsigned r;
  asm("v_cvt_pk_bf16_f32 %0, %1, %2" : "=v"(r) : "v"(a), "v"(b));
  return r;
}

// exchange: a.lanes[32:63] <-> b.lanes[0:31]
static __device__ __forceinline__ void swap32(unsigned& a, unsigned& b) {
  asm("v_permlane32_swap_b32 %0, %1" : "+v"(a), "+v"(b));
}

static __device__ __forceinline__ void async_copy16(const void* g, void* l) {
  __builtin_amdgcn_global_load_lds(
      (const __attribute__((address_space(1))) unsigned int*)g,
      (__attribute__((address_space(3))) unsigned int*)l, 16, 0, 0);
}

// ---------------- elementwise fp32 -> bf16 cast ----------------
__global__ __launch_bounds__(256) void k_cvt_bf16x4(const float* __restrict__ in,
                                                    ushort4* __restrict__ out, int n4) {
  int i = blockIdx.x * blockDim.x + threadIdx.x;
  if (i >= n4) return;
  float4 v = ((const float4*)in)[i];
  out[i] = make_ushort4(f2bf(v.x), f2bf(v.y), f2bf(v.z), f2bf(v.w));
}

// ---------------- fp32 [R][C] -> bf16 [C][R] transpose ----------------
__global__ __launch_bounds__(256) void k_transpose_bf(const float* __restrict__ in,
                                                      unsigned short* __restrict__ out,
                                                      int R, int C) {
  __shared__ float tile[32][33];
  const int tx = threadIdx.x & 31, ty = threadIdx.x >> 5;  // ty 0..7
  const int r0 = blockIdx.y * 32, c0 = blockIdx.x * 32;
#pragma unroll
  for (int i = 0; i < 32; i += 8)
    tile[ty + i][tx] = in[(size_t)(r0 + ty + i) * C + c0 + tx];
  __syncthreads();
#pragma unroll
  for (int i = 0; i < 32; i += 8)
    out[(size_t)(c0 + ty + i) * R + r0 + tx] = f2bf(tile[tx][ty + i]);
}

// ---------------- shared GEMM core: C[128x128] tile, K=1024, A[M][K] bf16, BT[N][K] bf16 ----------------
__device__ __forceinline__ void gemm_core_k1024(const unsigned short* __restrict__ A,
                                                const unsigned short* __restrict__ BT,
                                                int m0, int n0,
                                                unsigned short* sA, unsigned short* sB,
                                                f32x4 acc[4][4]) {
  const int tid = threadIdx.x;
  const int wave = tid >> 6, lane = tid & 63;
  const int wm = wave >> 1, wn = wave & 1;

  const unsigned short* gsrc = (wave < 2) ? A : BT;
  const int row0 = (wave < 2) ? m0 : n0;
  unsigned short* lbase = (wave < 2) ? sA : sB;
  const int cw = (wave & 1) * 4;
  const size_t gr = (size_t)(row0 + cw * 16 + (lane >> 2)) * TK + (lane & 3) * 8;

#pragma unroll
  for (int mi = 0; mi < 4; ++mi)
#pragma unroll
    for (int ni = 0; ni < 4; ++ni)
      acc[mi][ni] = (f32x4){0.f, 0.f, 0.f, 0.f};

  auto stage = [&](int buf, int kt) {
    const unsigned short* g = gsrc + gr + kt * 32;
    unsigned short* l = lbase + buf * 4096 + cw * 512;
#pragma unroll
    for (int c = 0; c < 4; ++c)
      async_copy16(g + (size_t)c * 16 * TK, l + c * 512);
  };

  stage(0, 0);
  __syncthreads();

  const int l15 = lane & 15, lk8 = (lane >> 4) * 8;
  const int aoff = (wm * 64 + l15) * 32 + lk8;
  const int boff = (wn * 64 + l15) * 32 + lk8;

  for (int kt = 0; kt < TK / 32; ++kt) {
    const int buf = kt & 1;
    if (kt + 1 < TK / 32) stage(buf ^ 1, kt + 1);
    short8 af[4], bfr[4];
#pragma unroll
    for (int i = 0; i < 4; ++i) {
      af[i] = *(const short8*)&sA[buf * 4096 + aoff + i * 16 * 32];
      bfr[i] = *(const short8*)&sB[buf * 4096 + boff + i * 16 * 32];
    }
#pragma unroll
    for (int mi = 0; mi < 4; ++mi)
#pragma unroll
      for (int ni = 0; ni < 4; ++ni)
        acc[mi][ni] = __builtin_amdgcn_mfma_f32_16x16x32_bf16(af[mi], bfr[ni], acc[mi][ni], 0, 0, 0);
    __syncthreads();
  }
}

// ---------------- GEMM1: qkv = xb @ waT^T + bias -> Q/K [B,H,S,HS] and VT [B,H,HS,S] ----------------
// T1 XCD swizzle: dispatch-linear bid -> XCD bid&7 owns a contiguous m-band (4 row-blocks
// = 512 rows, A-panel 1 MB -> L2-resident per XCD). Bijective (768 = 8 x 96).
__global__ __launch_bounds__(256) void k_gemm_qkv(const unsigned short* __restrict__ A,
                                                  const unsigned short* __restrict__ BT,
                                                  const float* __restrict__ bias,
                                                  unsigned short* __restrict__ Qo,
                                                  unsigned short* __restrict__ Ko,
                                                  unsigned short* __restrict__ VTo) {
  __shared__ unsigned short smem[4 * 64 * 68];  // 34816 B; front 32 KB doubles as sA/sB
  unsigned short* sA = smem;
  unsigned short* sB = smem + 8192;
  f32x4 acc[4][4];
  const int bid = blockIdx.y * 24 + blockIdx.x;   // dispatch-linear (x fastest)
  const int swz = (bid & 7) * 96 + (bid >> 3);    // XCD-contiguous remap
  const int m0 = (swz / 24) * 128, n0 = (swz % 24) * 128;
  gemm_core_k1024(A, BT, m0, n0, sA, sB, acc);

  const int lane = threadIdx.x & 63, wave = threadIdx.x >> 6;
  const int wm = wave >> 1, wn = wave & 1;
  const int lr4 = (lane >> 4) * 4, l15 = lane & 15;

  const int col0 = n0 + wn * 64;   // 64-aligned -> one head, one region (uniform per wave)
  const int reg = col0 >> 10;      // 0:q 1:k 2:v
  const int h0 = (col0 & 1023) >> 6;
  const bool isV = (reg == 2);
  const int t0 = m0 + wm * 64;     // first row of this wave's subtile
  const int b = t0 >> 11;
  const int s0 = t0 & 2047;

  unsigned short* tw = smem + wave * (64 * 68);
#pragma unroll
  for (int mi = 0; mi < 4; ++mi) {
#pragma unroll
    for (int ni = 0; ni < 4; ++ni) {
      const int c = ni * 16 + l15;
      const float bi = bias[col0 + c];
#pragma unroll
      for (int j = 0; j < 4; ++j) {
        const int r = mi * 16 + lr4 + j;
        tw[isV ? (c * 68 + r) : (r * 68 + c)] = f2bf(acc[mi][ni][j] + bi);
      }
    }
  }
  unsigned short* outp;
  size_t rstride;
  if (isV) {        // row = d, cols = s
    outp = VTo + (((size_t)b * TH + h0) * THS) * TS + s0;
    rstride = TS;
  } else {          // row = s, cols = d
    outp = (reg == 0 ? Qo : Ko) + (((size_t)b * TH + h0) * TS + s0) * THS;
    rstride = THS;
  }
#pragma unroll
  for (int p2 = 0; p2 < 8; ++p2) {
    const int rp = p2 * 8 + (lane >> 3);
    const int co = (lane & 7) * 8;
    union { short4v h[2]; short8 s8; } u;
    u.h[0] = *(const short4v*)&tw[rp * 68 + co];
    u.h[1] = *(const short4v*)&tw[rp * 68 + co + 4];
    *(short8*)(outp + (size_t)rp * rstride + co) = u.s8;
  }
}

// ---------------- flash attention, causal, T15 2-deep pipelined ----------------
// R2 structure (grid (16,16,2), b-complement, 4 barrier-free waves x 32 q-rows, KVBLK=32)
// + software pipeline: QK^T(t+1) issues on the MFMA pipe BEFORE softmax(t) runs on the
// VALU pipe -> the serial QK->softmax dependency leaves the per-tile critical path.
// Two-phase unroll with named sA/sB, kfA/kfB (rule #20: no runtime-indexed regs).
// + defer-rescale (T13) and tree reductions (both proven R8/R9). ~155 VGPR; grid gives
// only 2 waves/SIMD so no occupancy loss below 256 VGPR.
__global__ __launch_bounds__(256) void k_attn(const unsigned short* __restrict__ Q,
                                              const unsigned short* __restrict__ K,
                                              const unsigned short* __restrict__ VT,
                                              unsigned short* __restrict__ attn) {
  __shared__ unsigned short sO[4][32 * 68];  // per-wave O transpose buffer, stride 68
  const int lane = threadIdx.x & 63, wave = threadIdx.x >> 6;
  const int l31 = lane & 31, h = lane >> 5;
  int qt = blockIdx.x;
  const int hh = blockIdx.y, b = blockIdx.z;
  if (b) qt = 15 - qt;  // complement pairing balances the causal triangle across CUs
  const int qrb = qt * 128 + wave * 32;

  const unsigned short* Qh = Q + (((size_t)b * TH + hh) * TS) * THS;
  const unsigned short* Kh = K + (((size_t)b * TH + hh) * TS) * THS;
  const unsigned short* Vh = VT + (((size_t)b * TH + hh) * THS) * TS;

  short8 qf[4];
#pragma unroll
  for (int c2 = 0; c2 < 4; ++c2)
    qf[c2] = *(const short8*)&Qh[(size_t)(qrb + l31) * THS + c2 * 16 + h * 8];

  f32x16 o0 = {}, o1 = {};
  float m_run = -1e30f, l_run = 0.f;
  const float cl2e = 0.125f * 1.44269504088896340736f;  // scale * log2(e)
  const float THR = 8.0f / cl2e;                        // defer-rescale threshold

  const int nkt = (qrb >> 5) + 1;  // wave-uniform

  // prologue: K0 -> kfA -> sA; K1 -> kfB
  short8 kfA[4], kfB[4];
#pragma unroll
  for (int c2 = 0; c2 < 4; ++c2)
    kfA[c2] = *(const short8*)&Kh[(size_t)l31 * THS + c2 * 16 + h * 8];
  f32x16 sA = {}, sB = {};
#pragma unroll
  for (int c2 = 0; c2 < 4; ++c2)
    sA = __builtin_amdgcn_mfma_f32_32x32x16_bf16(kfA[c2], qf[c2], sA, 0, 0, 0);
  if (nkt > 1) {
#pragma unroll
    for (int c2 = 0; c2 < 4; ++c2)
      kfB[c2] = *(const short8*)&Kh[(size_t)(32 + l31) * THS + c2 * 16 + h * 8];
  }

  // phase: consume sCur (tile t); compute sNxt from kfN (tile t+1); reload kfP = K_{t+2}.
  auto phase = [&](f32x16& sCur, f32x16& sNxt, short8 (&kfN)[4], short8 (&kfP)[4],
                   const int t) {
    const int kb = t * 32;
    // V^T frags for tile t (consumed at the bottom -> full-iteration latency cover)
    short8 vf00 = *(const short8*)&Vh[(size_t)l31 * TS + kb + h * 8];
    short8 vf01 = *(const short8*)&Vh[(size_t)l31 * TS + kb + 16 + h * 8];
    short8 vf10 = *(const short8*)&Vh[(size_t)(32 + l31) * TS + kb + h * 8];
    short8 vf11 = *(const short8*)&Vh[(size_t)(32 + l31) * TS + kb + 16 + h * 8];

    // next tile's scores on the MFMA pipe (independent of this tile's softmax)
    if (t + 1 < nkt) {
      sNxt = (f32x16){};
#pragma unroll
      for (int c2 = 0; c2 < 4; ++c2)
        sNxt = __builtin_amdgcn_mfma_f32_32x32x16_bf16(kfN[c2], qf[c2], sNxt, 0, 0, 0);
    }
    // prefetch K_{t+2} into the now-free kfP
    if (t + 2 < nkt) {
#pragma unroll
      for (int c2 = 0; c2 < 4; ++c2)
        kfP[c2] = *(const short8*)&Kh[(size_t)(kb + 64 + l31) * THS + c2 * 16 + h * 8];
    }

    // causal mask on the diagonal tile (applied at consumption)
    if (t == nkt - 1) {
#pragma unroll
      for (int r = 0; r < 16; ++r)
        if ((r & 3) + 8 * (r >> 2) + 4 * h > l31) sCur[r] = -1e30f;
    }

    // online softmax on sCur (tree reductions; per-lane q = l31)
    const float ma = fmaxf(fmaxf(sCur[0], sCur[1]), fmaxf(sCur[2], sCur[3]));
    const float mb = fmaxf(fmaxf(sCur[4], sCur[5]), fmaxf(sCur[6], sCur[7]));
    const float mc = fmaxf(fmaxf(sCur[8], sCur[9]), fmaxf(sCur[10], sCur[11]));
    const float md = fmaxf(fmaxf(sCur[12], sCur[13]), fmaxf(sCur[14], sCur[15]));
    float tm = fmaxf(fmaxf(ma, mb), fmaxf(mc, md));
    tm = fmaxf(tm, __shfl_xor(tm, 32));

    float al;
    if (__all(tm <= m_run + THR)) {
      al = 1.0f;  // defer: keep old max, P bounded by exp2(8)
    } else {
      const float mn = fmaxf(m_run, tm);
      al = __builtin_amdgcn_exp2f((m_run - mn) * cl2e);
      m_run = mn;
      o0 *= al;
      o1 *= al;
    }
#pragma unroll
    for (int r = 0; r < 16; ++r)
      sCur[r] = __builtin_amdgcn_exp2f((sCur[r] - m_run) * cl2e);
    const float sa = (sCur[0] + sCur[1]) + (sCur[2] + sCur[3]);
    const float sb2 = (sCur[4] + sCur[5]) + (sCur[6] + sCur[7]);
    const float sc = (sCur[8] + sCur[9]) + (sCur[10] + sCur[11]);
    const float sd = (sCur[12] + sCur[13]) + (sCur[14] + sCur[15]);
    float ts = (sa + sb2) + (sc + sd);
    ts += __shfl_xor(ts, 32);
    l_run = l_run * al + ts;

    // P^T -> bf16 B-frags (cvt_pk + permlane32_swap)
    unsigned B0 = cvtpk(sCur[0], sCur[1]), B1 = cvtpk(sCur[2], sCur[3]);
    unsigned B2 = cvtpk(sCur[4], sCur[5]), B3 = cvtpk(sCur[6], sCur[7]);
    swap32(B0, B2);
    swap32(B1, B3);
    unsigned B4 = cvtpk(sCur[8], sCur[9]), B5 = cvtpk(sCur[10], sCur[11]);
    unsigned B6 = cvtpk(sCur[12], sCur[13]), B7 = cvtpk(sCur[14], sCur[15]);
    swap32(B4, B6);
    swap32(B5, B7);
    union U { uint4v u; short8 s8; } u0, u1;
    u0.u = (uint4v){B0, B1, B2, B3};
    u1.u = (uint4v){B4, B5, B6, B7};

    o0 = __builtin_amdgcn_mfma_f32_32x32x16_bf16(vf00, u0.s8, o0, 0, 0, 0);
    o0 = __builtin_amdgcn_mfma_f32_32x32x16_bf16(vf01, u1.s8, o0, 0, 0, 0);
    o1 = __builtin_amdgcn_mfma_f32_32x32x16_bf16(vf10, u0.s8, o1, 0, 0, 0);
    o1 = __builtin_amdgcn_mfma_f32_32x32x16_bf16(vf11, u1.s8, o1, 0, 0, 0);
  };

  for (int t = 0; t < nkt; t += 2) {
    phase(sA, sB, kfB, kfA, t);
    if (t + 1 < nkt) phase(sB, sA, kfA, kfB, t + 1);
  }

  // epilogue: O^T -> LDS (wave-private, no barrier needed) -> coalesced global store
  const float inv = 1.0f / l_run;
  unsigned* so32 = (unsigned*)&sO[wave][0];
#pragma unroll
  for (int j2 = 0; j2 < 8; ++j2) {
    const int d0 = ((2 * j2) & 3) + 8 * (j2 >> 1) + 4 * h;  // even d of the pair
    so32[l31 * 34 + (d0 >> 1)] = cvtpk(o0[2 * j2] * inv, o0[2 * j2 + 1] * inv);
    so32[l31 * 34 + ((32 + d0) >> 1)] = cvtpk(o1[2 * j2] * inv, o1[2 * j2 + 1] * inv);
  }
#pragma unroll
  for (int p2 = 0; p2 < 4; ++p2) {
    const int rp = p2 * 8 + (lane >> 3);
    const int co = (lane & 7) * 8;
    short4v va = *(const short4v*)&sO[wave][rp * 68 + co];
    short4v vb = *(const short4v*)&sO[wave][rp * 68 + co + 4];
    unsigned short* gp = &attn[(size_t)(b * TS + qrb + rp) * TD + hh * THS + co];
    *(short4v*)gp = va;
    *(short4v*)(gp + 4) = vb;
  }
}

// ---------------- GEMM2: out = attn @ wpT^T + bias (fp32 out) ----------------
// 128M x 64N tile, 512 blocks = 2/CU (R11). T1 XCD swizzle added: per-XCD m-band ->
// A-panel 1 MB + B (2 MB) both L2-resident. Bijective (512 = 8 x 64).
__global__ __launch_bounds__(256) void k_gemm_proj(const unsigned short* __restrict__ A,
                                                   const unsigned short* __restrict__ BT,
                                                   const float* __restrict__ bias,
                                                   float* __restrict__ out) {
  __shared__ unsigned short sA[2 * 4096];  // 2 bufs x 128x32
  __shared__ unsigned short sB[2 * 2048];  // 2 bufs x 64x32
  const int tid = threadIdx.x;
  const int wave = tid >> 6, lane = tid & 63;
  const int wm = wave >> 1, wn = wave & 1;
  const int bid = blockIdx.y * 16 + blockIdx.x;   // dispatch-linear
  const int swz = (bid & 7) * 64 + (bid >> 3);    // XCD-contiguous remap
  const int m0 = (swz / 16) * 128, n0 = (swz % 16) * 64;

  f32x4 acc[4][2];
#pragma unroll
  for (int mi = 0; mi < 4; ++mi)
#pragma unroll
    for (int nj = 0; nj < 2; ++nj)
      acc[mi][nj] = (f32x4){0.f, 0.f, 0.f, 0.f};

  const int ar0 = tid >> 2, ak0 = (tid & 3) * 8;
  const size_t gA0 = (size_t)(m0 + ar0) * TK + ak0;
  const size_t gA1 = (size_t)(m0 + 64 + ar0) * TK + ak0;
  const size_t gB0 = (size_t)(n0 + ar0) * TK + ak0;  // ar0 < 64 for B rows

  auto stage = [&](int buf, int kt) {
    const int ko = kt * 32;
    async_copy16(A + gA0 + ko, sA + buf * 4096 + tid * 8);
    async_copy16(A + gA1 + ko, sA + buf * 4096 + 2048 + tid * 8);
    async_copy16(BT + gB0 + ko, sB + buf * 2048 + tid * 8);
  };

  stage(0, 0);
  __syncthreads();

  const int l15 = lane & 15, lk8 = (lane >> 4) * 8;
  const int aoff = (wm * 64 + l15) * 32 + lk8;
  const int boff = (wn * 32 + l15) * 32 + lk8;

  for (int kt = 0; kt < TK / 32; ++kt) {
    const int buf = kt & 1;
    if (kt + 1 < TK / 32) stage(buf ^ 1, kt + 1);
    short8 af[4], bfr[2];
#pragma unroll
    for (int i = 0; i < 4; ++i)
      af[i] = *(const short8*)&sA[buf * 4096 + aoff + i * 16 * 32];
#pragma unroll
    for (int j = 0; j < 2; ++j)
      bfr[j] = *(const short8*)&sB[buf * 2048 + boff + j * 16 * 32];
#pragma unroll
    for (int mi = 0; mi < 4; ++mi)
#pragma unroll
      for (int nj = 0; nj < 2; ++nj)
        acc[mi][nj] = __builtin_amdgcn_mfma_f32_16x16x32_bf16(af[mi], bfr[nj], acc[mi][nj], 0, 0, 0);
    __syncthreads();
  }

  const int lr4 = (lane >> 4) * 4;
#pragma unroll
  for (int mi = 0; mi < 4; ++mi) {
    const int row = m0 + wm * 64 + mi * 16 + lr4;
#pragma unroll
    for (int nj = 0; nj < 2; ++nj) {
      const int col = n0 + wn * 32 + nj * 16 + l15;
      const float bi = bias[col];
#pragma unroll
      for (int j = 0; j < 4; ++j)
        out[(size_t)(row + j) * TD + col] = acc[mi][nj][j] + bi;
    }
  }
}

extern "C" void kernel_launch(void* const* d_in, const int* in_sizes, int n_in,
                              void* d_out, int out_size, void* d_ws, size_t ws_size,
                              hipStream_t stream) {
  const float* x = (const float*)d_in[0];
  const float* c_attn_w = (const float*)d_in[1];
  const float* c_attn_b = (const float*)d_in[2];
  const float* c_proj_w = (const float*)d_in[3];
  const float* c_proj_b = (const float*)d_in[4];
  float* out = (float*)d_out;

  const size_t SZ_XB = (size_t)4096 * 1024 * 2;
  const size_t SZ_WAT = (size_t)3072 * 1024 * 2;
  const size_t SZ_WPT = (size_t)1024 * 1024 * 2;
  const size_t SZ_HEAD = (size_t)TB * TH * TS * THS * 2;
  const size_t SZ_ATT = (size_t)4096 * 1024 * 2;
  if (ws_size < SZ_XB + SZ_WAT + SZ_WPT + 3 * SZ_HEAD + SZ_ATT) return;

  char* ws = (char*)d_ws;
  unsigned short* xb = (unsigned short*)ws;   ws += SZ_XB;
  unsigned short* waT = (unsigned short*)ws;  ws += SZ_WAT;
  unsigned short* wpT = (unsigned short*)ws;  ws += SZ_WPT;
  unsigned short* Qb = (unsigned short*)ws;   ws += SZ_HEAD;
  unsigned short* Kb = (unsigned short*)ws;   ws += SZ_HEAD;
  unsigned short* VTb = (unsigned short*)ws;  ws += SZ_HEAD;
  unsigned short* attn = (unsigned short*)ws; ws += SZ_ATT;

  k_cvt_bf16x4<<<4096, 256, 0, stream>>>(x, (ushort4*)xb, 4096 * 1024 / 4);
  k_transpose_bf<<<dim3(3072 / 32, 1024 / 32), 256, 0, stream>>>(c_attn_w, waT, 1024, 3072);
  k_transpose_bf<<<dim3(1024 / 32, 1024 / 32), 256, 0, stream>>>(c_proj_w, wpT, 1024, 1024);
  k_gemm_qkv<<<dim3(3072 / 128, 4096 / 128), 256, 0, stream>>>(xb, waT, c_attn_b, Qb, Kb, VTb);
  k_attn<<<dim3(16, TH, TB), 256, 0, stream>>>(Qb, Kb, VTb, attn);
  k_gemm_proj<<<dim3(1024 / 64, 4096 / 128), 256, 0, stream>>>(attn, wpT, c_proj_b, out);
}